// Round 6
// baseline (976.827 us; speedup 1.0000x reference)
//
#include <hip/hip_runtime.h>
#include <hip/hip_bf16.h>

// DisentangledSelfAttention: B=4096, S=64, E=64, A=256, H=4, HD=64.
// Head-per-wave, 256-thread blocks, 4 blocks/CU (LDS 37 KB).
// Associativity trick: P@(Xv@Wv+1 bv^T) = (P@Xv)@Wv + 2 bv^T  (rowsum P = 2),
// so no V^T staging buffer; Xv enters as B-fragments straight from global.
// All C->fragment relayouts (T, P, G) use one per-wave [16][72] LDS slice,
// mt-sliced: write rows quad*4+r, read rows lc of the same 16-row tile.
// Algebra: L_h = (C Xq)(Wq_h Wk_h^T)(C Xk)^T with M_h precomputed hi/lo bf16;
// bq/bk cancel under centering; bu cancels in softmax(axis=1);
// residual query@Wr = Xcq@Wr + rank-1 rho;  rho2 = rho + 2*bv.

#define B_ 4096

typedef __attribute__((ext_vector_type(8))) short bf16x8;
typedef __attribute__((ext_vector_type(4))) float f32x4;
typedef __attribute__((ext_vector_type(4))) short s16x4;

#define MFMA16(a, b, c) __builtin_amdgcn_mfma_f32_16x16x32_bf16((a), (b), (c), 0, 0, 0)

static __device__ __forceinline__ short f2b(float f) {  // RNE fp32->bf16
  union { float f; unsigned u; } x; x.f = f;
  unsigned r = x.u + 0x7fffu + ((x.u >> 16) & 1u);
  return (short)(r >> 16);
}
static __device__ __forceinline__ float b2f(short s) {
  union { unsigned u; float f; } x; x.u = ((unsigned)(unsigned short)s) << 16;
  return x.f;
}
static __device__ __forceinline__ unsigned cvtpk(float lo, float hi) {  // RNE pack
  unsigned r;
  asm volatile("v_cvt_pk_bf16_f32 %0, %1, %2" : "=v"(r) : "v"(lo), "v"(hi));
  return r;
}

// ws layout (units: shorts)
#define MTHI 0       // [h][e'][e] = hi(M_h[e][e']), M = Wq_h Wk_h^T   (4*64*64)
#define MTLO 16384   // lo part
#define WVT  32768   // [a][e] = Wv[e][a]
#define WRT  49152   // [a][e] = Wr[e][a]
#define WU0  65536   // [h][16][64], row m=0 = Wu[:,h], rows 1..15 = 0

__global__ __launch_bounds__(256)
void prepass(const float* __restrict__ Wq, const float* __restrict__ Wk,
             const float* __restrict__ Wv, const float* __restrict__ Wr,
             const float* __restrict__ Wu, short* __restrict__ ws) {
  int t = blockIdx.x * 256 + threadIdx.x;  // 0..16383
  int a = t >> 6, e = t & 63;
  ws[WVT + t] = f2b(Wv[e * 256 + a]);
  ws[WRT + t] = f2b(Wr[e * 256 + a]);
  if (t < 4096) {
    int h = t >> 10, m = (t >> 6) & 15, e2 = t & 63;
    ws[WU0 + t] = (m == 0) ? f2b(Wu[e2 * 4 + h]) : (short)0;
  }
  // M_h[e][e'] = sum_a Wq[e, h*64+a] * Wk[e', h*64+a], stored transposed [e'][e]
  int h = t >> 12, ep = (t >> 6) & 63;
  const float* wqr = Wq + e * 256 + h * 64;
  const float* wkr = Wk + ep * 256 + h * 64;
  float s = 0.f;
#pragma unroll 8
  for (int aa = 0; aa < 64; ++aa) s += wqr[aa] * wkr[aa];
  short hi = f2b(s);
  ws[MTHI + (h * 64 + ep) * 64 + e] = hi;
  ws[MTLO + (h * 64 + ep) * 64 + e] = f2b(s - b2f(hi));
}

__global__ __launch_bounds__(256, 4)
void attn_main(const float* __restrict__ query, const float* __restrict__ key_,
               const float* __restrict__ value, const float* __restrict__ bv,
               const float* __restrict__ br, const short* __restrict__ ws,
               float* __restrict__ out) {
  const int b    = blockIdx.x;
  const int tid  = threadIdx.x;
  const int w    = tid >> 6;    // wave id == head id
  const int lane = tid & 63;
  const int quad = lane >> 4;
  const int lc   = lane & 15;
  const int h    = w;

  __shared__ short XqH[64][72];     // centered query, hi bf16
  __shared__ short XqL[64][72];     // centered query, lo bf16
  __shared__ short Xk [64][72];     // centered key, single bf16
  __shared__ short buf[4][16][72];  // per-wave relayout slice (T -> P -> G)
  __shared__ float mq[64];          // query column means (for rho)
  // colsq/colsk overlap buf (dead after barrier 2)
  float* colsq = (float*)&buf[0][0][0];   // [4][64]
  float* colsk = colsq + 256;             // [4][64]
  // total LDS = 27648 + 9216 + 256 = 37120 B -> 4 blocks/CU

  // ================= load + centering phase (2 barriers) ===================
  const int crow = w * 16 + (lane >> 2);   // row this lane loads
  const int cg   = (lane & 3) * 16;        // col group base
  const float* qp = query + ((size_t)b * 64 + crow) * 64 + cg;
  const float* kp = key_  + ((size_t)b * 64 + crow) * 64 + cg;
  f32x4 qv[4], kv[4];
#pragma unroll
  for (int j = 0; j < 4; ++j) { qv[j] = *(const f32x4*)(qp + 4 * j); kv[j] = *(const f32x4*)(kp + 4 * j); }

  // issue Xv B-fragment loads early (consumed after barrier 2)
  // xvf[nt][kk][j] = value[b][key = kk*32+quad*8+j][e = nt*16+lc]
  float xvf[4][2][8];
  {
    const float* vbase = value + (size_t)b * 4096 + quad * 512 + lc;
#pragma unroll
    for (int nt = 0; nt < 4; ++nt)
#pragma unroll
      for (int kk = 0; kk < 2; ++kk)
#pragma unroll
        for (int j = 0; j < 8; ++j)
          xvf[nt][kk][j] = vbase[(kk * 32 + j) * 64 + nt * 16];
  }

  // partial column sums over this wave's 16 rows (rows live at lane bits 2..5)
  f32x4 sq[4], sk[4];
#pragma unroll
  for (int j = 0; j < 4; ++j) { sq[j] = qv[j]; sk[j] = kv[j]; }
#pragma unroll
  for (int off = 4; off <= 32; off <<= 1)
#pragma unroll
    for (int j = 0; j < 4; ++j)
#pragma unroll
      for (int c = 0; c < 4; ++c) {
        sq[j][c] += __shfl_xor(sq[j][c], off);
        sk[j][c] += __shfl_xor(sk[j][c], off);
      }
  if ((lane & 60) == 0) {  // lanes 0..3, one per col group
#pragma unroll
    for (int j = 0; j < 4; ++j) {
      *(f32x4*)&colsq[w * 64 + cg + 4 * j] = sq[j];
      *(f32x4*)&colsk[w * 64 + cg + 4 * j] = sk[j];
    }
  }
  __syncthreads();  // barrier 1: partial sums visible

  f32x4 mqv[4], mkv[4];
#pragma unroll
  for (int j = 0; j < 4; ++j) {
    f32x4 aq = {0.f, 0.f, 0.f, 0.f}, ak = {0.f, 0.f, 0.f, 0.f};
#pragma unroll
    for (int ww = 0; ww < 4; ++ww) {
      aq += *(const f32x4*)&colsq[ww * 64 + cg + 4 * j];
      ak += *(const f32x4*)&colsk[ww * 64 + cg + 4 * j];
    }
    mqv[j] = aq * (1.0f / 64.0f);
    mkv[j] = ak * (1.0f / 64.0f);
  }
  if (w == 0 && (lane & 60) == 0)
#pragma unroll
    for (int j = 0; j < 4; ++j) *(f32x4*)&mq[cg + 4 * j] = mqv[j];

  // center, split hi/lo, store to shared LDS
#pragma unroll
  for (int half = 0; half < 2; ++half) {
    bf16x8 qh8, ql8, k8;
#pragma unroll
    for (int jj = 0; jj < 8; ++jj) {
      int j = half * 2 + (jj >> 2), c = jj & 3;
      float cq = qv[j][c] - mqv[j][c];
      short hi = f2b(cq);
      qh8[jj] = hi;
      ql8[jj] = f2b(cq - b2f(hi));
      k8[jj]  = f2b(kv[j][c] - mkv[j][c]);
    }
    *(bf16x8*)&XqH[crow][cg + 8 * half] = qh8;
    *(bf16x8*)&XqL[crow][cg + 8 * half] = ql8;
    *(bf16x8*)&Xk [crow][cg + 8 * half] = k8;
  }

  // pack Xv B-fragments (waits on the early value loads)
  bf16x8 xvB[4][2];
#pragma unroll
  for (int nt = 0; nt < 4; ++nt)
#pragma unroll
    for (int kk = 0; kk < 2; ++kk) {
      union { unsigned u[4]; bf16x8 v; } pk;
#pragma unroll
      for (int p = 0; p < 4; ++p)
        pk.u[p] = cvtpk(xvf[nt][kk][2 * p], xvf[nt][kk][2 * p + 1]);
      xvB[nt][kk] = pk.v;
    }
  __syncthreads();  // barrier 2: Xq/Xk/mq visible. No more barriers.

  // ================= per-head phase (wave-private, barrier-free) ============
  // rho2[d=lane] = mu_q . Wr[:, h*64+lane] + br[h*64+lane] + 2*bv[h*64+lane]
  float rho;
  {
    const short* wrr = ws + WRT + (h * 64 + lane) * 64;
    float acc = br[h * 64 + lane] + 2.0f * bv[h * 64 + lane];
#pragma unroll
    for (int e8 = 0; e8 < 8; ++e8) {
      bf16x8 w8 = *(const bf16x8*)(wrr + e8 * 8);
#pragma unroll
      for (int j = 0; j < 8; ++j) acc += mq[e8 * 8 + j] * b2f(w8[j]);
    }
    rho = acc;
  }
  float rr[4];
#pragma unroll
  for (int nt = 0; nt < 4; ++nt) rr[nt] = __shfl(rho, nt * 16 + lc);

  // ---- unary: u = softmax_s( Xck @ Wu[:,h] ) -> usm[nt] = u[nt*16+lc] ----
  float usm[4];
  {
    bf16x8 wu[2];
#pragma unroll
    for (int kk = 0; kk < 2; ++kk)
      wu[kk] = *(const bf16x8*)(ws + WU0 + h * 1024 + lc * 64 + kk * 32 + quad * 8);
    f32x4 aU[4];
#pragma unroll
    for (int nt = 0; nt < 4; ++nt) {
      aU[nt] = f32x4{0.f, 0.f, 0.f, 0.f};
#pragma unroll
      for (int kk = 0; kk < 2; ++kk) {
        bf16x8 xb = *(const bf16x8*)&Xk[nt * 16 + lc][kk * 32 + quad * 8];
        aU[nt] = MFMA16(wu[kk], xb, aU[nt]);
      }
    }
    float un[4];
#pragma unroll
    for (int nt = 0; nt < 4; ++nt) un[nt] = __shfl(aU[nt][0], lc);  // u[nt*16+lc]
    float um = fmaxf(fmaxf(un[0], un[1]), fmaxf(un[2], un[3]));
    um = fmaxf(um, __shfl_xor(um, 1)); um = fmaxf(um, __shfl_xor(um, 2));
    um = fmaxf(um, __shfl_xor(um, 4)); um = fmaxf(um, __shfl_xor(um, 8));
    float ue[4], us = 0.f;
#pragma unroll
    for (int nt = 0; nt < 4; ++nt) { ue[nt] = __expf(un[nt] - um); us += ue[nt]; }
    us += __shfl_xor(us, 1); us += __shfl_xor(us, 2);
    us += __shfl_xor(us, 4); us += __shfl_xor(us, 8);
    float uinv = __builtin_amdgcn_rcpf(us);
#pragma unroll
    for (int nt = 0; nt < 4; ++nt) usm[nt] = ue[nt] * uinv;
  }

  // ---- per q-row-tile chain: T -> L -> softmax/P -> G=P@Xv -> out=G@Wv ----
  for (int mt = 0; mt < 4; ++mt) {
    // Xq fragments for this tile (used by T and by the Wr residual)
    bf16x8 xh[2], xl[2];
#pragma unroll
    for (int kk = 0; kk < 2; ++kk) {
      xh[kk] = *(const bf16x8*)&XqH[mt * 16 + lc][kk * 32 + quad * 8];
      xl[kk] = *(const bf16x8*)&XqL[mt * 16 + lc][kk * 32 + quad * 8];
    }

    // T(own 16 rows) = Xcq @ M_h  (3-term hi/lo)
    {
      f32x4 aT[4];
#pragma unroll
      for (int nt = 0; nt < 4; ++nt) {
        f32x4 acc = {0.f, 0.f, 0.f, 0.f};
#pragma unroll
        for (int kk = 0; kk < 2; ++kk) {
          int off = h * 4096 + (nt * 16 + lc) * 64 + kk * 32 + quad * 8;
          bf16x8 mh = *(const bf16x8*)(ws + MTHI + off);
          bf16x8 ml = *(const bf16x8*)(ws + MTLO + off);
          acc = MFMA16(xh[kk], mh, acc);
          acc = MFMA16(xh[kk], ml, acc);
          acc = MFMA16(xl[kk], mh, acc);
        }
        aT[nt] = acc;
      }
#pragma unroll
      for (int nt = 0; nt < 4; ++nt)
#pragma unroll
        for (int r = 0; r < 4; ++r)
          buf[w][quad * 4 + r][nt * 16 + lc] = f2b(aT[nt][r]);
    }
    bf16x8 tA[2];
#pragma unroll
    for (int kk = 0; kk < 2; ++kk)
      tA[kk] = *(const bf16x8*)&buf[w][lc][kk * 32 + quad * 8];

    // L(own rows) = T @ Xck^T
    f32x4 aL[4];
#pragma unroll
    for (int nt = 0; nt < 4; ++nt) {
      f32x4 acc = {0.f, 0.f, 0.f, 0.f};
#pragma unroll
      for (int kk = 0; kk < 2; ++kk) {
        bf16x8 xkB = *(const bf16x8*)&Xk[nt * 16 + lc][kk * 32 + quad * 8];
        acc = MFMA16(tA[kk], xkB, acc);
      }
      aL[nt] = acc;
    }

    // row softmax + unary; P -> slice
#pragma unroll
    for (int r = 0; r < 4; ++r) {
      float m = fmaxf(fmaxf(aL[0][r], aL[1][r]), fmaxf(aL[2][r], aL[3][r]));
      m = fmaxf(m, __shfl_xor(m, 1)); m = fmaxf(m, __shfl_xor(m, 2));
      m = fmaxf(m, __shfl_xor(m, 4)); m = fmaxf(m, __shfl_xor(m, 8));
      float e0 = __expf(aL[0][r] - m), e1 = __expf(aL[1][r] - m);
      float e2 = __expf(aL[2][r] - m), e3 = __expf(aL[3][r] - m);
      float s = e0 + e1 + e2 + e3;
      s += __shfl_xor(s, 1); s += __shfl_xor(s, 2);
      s += __shfl_xor(s, 4); s += __shfl_xor(s, 8);
      float inv = __builtin_amdgcn_rcpf(s);
      buf[w][quad * 4 + r][lc]      = f2b(e0 * inv + usm[0]);
      buf[w][quad * 4 + r][16 + lc] = f2b(e1 * inv + usm[1]);
      buf[w][quad * 4 + r][32 + lc] = f2b(e2 * inv + usm[2]);
      buf[w][quad * 4 + r][48 + lc] = f2b(e3 * inv + usm[3]);
    }
    bf16x8 pA[2];
#pragma unroll
    for (int kk = 0; kk < 2; ++kk)
      pA[kk] = *(const bf16x8*)&buf[w][lc][kk * 32 + quad * 8];

    // G(own rows) = P @ Xv
    {
      f32x4 aG[4];
#pragma unroll
      for (int nt = 0; nt < 4; ++nt) {
        f32x4 acc = {0.f, 0.f, 0.f, 0.f};
#pragma unroll
        for (int kk = 0; kk < 2; ++kk) acc = MFMA16(pA[kk], xvB[nt][kk], acc);
        aG[nt] = acc;
      }
#pragma unroll
      for (int nt = 0; nt < 4; ++nt)
#pragma unroll
        for (int r = 0; r < 4; ++r)
          buf[w][quad * 4 + r][nt * 16 + lc] = f2b(aG[nt][r]);
    }
    bf16x8 gA[2];
#pragma unroll
    for (int kk = 0; kk < 2; ++kk)
      gA[kk] = *(const bf16x8*)&buf[w][lc][kk * 32 + quad * 8];

    // out(own rows) = G @ Wv_h + Xcq @ Wr_h (2-term) + rho2
#pragma unroll
    for (int nt = 0; nt < 4; ++nt) {
      f32x4 acc = {0.f, 0.f, 0.f, 0.f};
#pragma unroll
      for (int kk = 0; kk < 2; ++kk) {
        bf16x8 wv8 = *(const bf16x8*)(ws + WVT + (h * 64 + nt * 16 + lc) * 64 + kk * 32 + quad * 8);
        acc = MFMA16(gA[kk], wv8, acc);
        bf16x8 wr8 = *(const bf16x8*)(ws + WRT + (h * 64 + nt * 16 + lc) * 64 + kk * 32 + quad * 8);
        acc = MFMA16(xh[kk], wr8, acc);
        acc = MFMA16(xl[kk], wr8, acc);
      }
      float* op = out + ((size_t)b * 64 + mt * 16 + quad * 4) * 256 + h * 64 + nt * 16 + lc;
#pragma unroll
      for (int r = 0; r < 4; ++r) op[(size_t)r * 256] = acc[r] + rr[nt];
    }
  }
}

extern "C" void kernel_launch(void* const* d_in, const int* in_sizes, int n_in,
                              void* d_out, int out_size, void* d_ws, size_t ws_size,
                              hipStream_t stream) {
  (void)in_sizes; (void)n_in; (void)out_size; (void)ws_size;
  const float* query = (const float*)d_in[0];
  const float* key_  = (const float*)d_in[1];
  const float* value = (const float*)d_in[2];
  const float* Wq    = (const float*)d_in[3];
  // d_in[4] = bq: cancels under mean-centering
  const float* Wk    = (const float*)d_in[5];
  // d_in[6] = bk: cancels under mean-centering
  const float* Wv    = (const float*)d_in[7];
  const float* bv    = (const float*)d_in[8];
  const float* Wu    = (const float*)d_in[9];
  // d_in[10] = bu: cancels in softmax over fields
  const float* Wr    = (const float*)d_in[11];
  const float* br    = (const float*)d_in[12];
  short* ws = (short*)d_ws;

  hipLaunchKernelGGL(prepass, dim3(64), dim3(256), 0, stream, Wq, Wk, Wv, Wr, Wu, ws);
  hipLaunchKernelGGL(attn_main, dim3(B_), dim3(256), 0, stream,
                     query, key_, value, bv, br, ws, (float*)d_out);
}

// Round 7
// 524.010 us; speedup vs baseline: 1.8641x; 1.8641x over previous
//
#include <hip/hip_runtime.h>
#include <hip/hip_bf16.h>

// DisentangledSelfAttention: B=4096, S=64, E=64, A=256, H=4, HD=64.
// Head-per-wave, 256-thread blocks. Baseline-272us structure with LDS cut
// 67->37 KB (4 blocks/CU): the [64][72] scratch is replaced by a per-wave
// [16][72] slice reused sequentially (V^T per d-tile; then per q-tile
// T->L->softmax->P->out fused chain). All relayouts wave-internal, no
// barriers after centering.
// Algebra: L_h = (C Xq)(Wq_h Wk_h^T)(C Xk)^T, M_h precomputed hi/lo bf16;
// bq/bk cancel under centering; bu cancels in softmax(axis=1);
// residual query@Wr = Xcq@Wr + rank-1 rho.

#define B_ 4096

typedef __attribute__((ext_vector_type(8))) short bf16x8;
typedef __attribute__((ext_vector_type(4))) float f32x4;
typedef __attribute__((ext_vector_type(4))) short s16x4;

#define MFMA16(a, b, c) __builtin_amdgcn_mfma_f32_16x16x32_bf16((a), (b), (c), 0, 0, 0)

static __device__ __forceinline__ short f2b(float f) {  // RNE fp32->bf16
  union { float f; unsigned u; } x; x.f = f;
  unsigned r = x.u + 0x7fffu + ((x.u >> 16) & 1u);
  return (short)(r >> 16);
}
static __device__ __forceinline__ float b2f(short s) {
  union { unsigned u; float f; } x; x.u = ((unsigned)(unsigned short)s) << 16;
  return x.f;
}

// ws layout (units: shorts)
#define MTHI 0       // [h][e'][e] = hi(M_h[e][e']), M = Wq_h Wk_h^T   (4*64*64)
#define MTLO 16384   // lo part
#define WVT  32768   // [a][e] = Wv[e][a]
#define WRT  49152   // [a][e] = Wr[e][a]
#define WU0  65536   // [h][16][64], row m=0 = Wu[:,h], rows 1..15 = 0

__global__ __launch_bounds__(256)
void prepass(const float* __restrict__ Wq, const float* __restrict__ Wk,
             const float* __restrict__ Wv, const float* __restrict__ Wr,
             const float* __restrict__ Wu, short* __restrict__ ws) {
  int t = blockIdx.x * 256 + threadIdx.x;  // 0..16383
  int a = t >> 6, e = t & 63;
  ws[WVT + t] = f2b(Wv[e * 256 + a]);
  ws[WRT + t] = f2b(Wr[e * 256 + a]);
  if (t < 4096) {
    int h = t >> 10, m = (t >> 6) & 15, e2 = t & 63;
    ws[WU0 + t] = (m == 0) ? f2b(Wu[e2 * 4 + h]) : (short)0;
  }
  // M_h[e][e'] = sum_a Wq[e, h*64+a] * Wk[e', h*64+a], stored transposed [e'][e]
  int h = t >> 12, ep = (t >> 6) & 63;
  const float* wqr = Wq + e * 256 + h * 64;
  const float* wkr = Wk + ep * 256 + h * 64;
  float s = 0.f;
#pragma unroll 8
  for (int aa = 0; aa < 64; ++aa) s += wqr[aa] * wkr[aa];
  short hi = f2b(s);
  ws[MTHI + (h * 64 + ep) * 64 + e] = hi;
  ws[MTLO + (h * 64 + ep) * 64 + e] = f2b(s - b2f(hi));
}

__global__ __launch_bounds__(256, 2)
void attn_main(const float* __restrict__ query, const float* __restrict__ key_,
               const float* __restrict__ value, const float* __restrict__ bv,
               const float* __restrict__ br, const short* __restrict__ ws,
               float* __restrict__ out) {
  const int b    = blockIdx.x;
  const int tid  = threadIdx.x;
  const int w    = tid >> 6;    // wave id == head id
  const int lane = tid & 63;
  const int quad = lane >> 4;
  const int lc   = lane & 15;
  const int h    = w;

  __shared__ short XqH[64][72];       // centered query, hi bf16
  __shared__ short XqL[64][72];       // centered query, lo bf16
  __shared__ short Xk [64][72];       // centered key, single bf16
  __shared__ short slice[4][16][72];  // per-wave relayout slice (VT/T/P)
  __shared__ float mq[64];            // query column means (for rho)
  // colsq/colsk overlap slice (dead after barrier 2); 512 floats <= 576
  float* colsq = (float*)&slice[0][0][0];   // [4][64]
  float* colsk = colsq + 256;               // [4][64]
  // total LDS = 27648 + 9216 + 256 = 37120 B -> 4 blocks/CU at VGPR<=128

  // ================= centering phase (2 barriers, then barrier-free) ========
  const int crow = w * 16 + (lane >> 2);   // row this lane loads
  const int cg   = (lane & 3) * 16;        // col group base
  const float* qp = query + ((size_t)b * 64 + crow) * 64 + cg;
  const float* kp = key_  + ((size_t)b * 64 + crow) * 64 + cg;
  f32x4 qv[4], kv[4];
#pragma unroll
  for (int j = 0; j < 4; ++j) { qv[j] = *(const f32x4*)(qp + 4 * j); kv[j] = *(const f32x4*)(kp + 4 * j); }

  // partial column sums over this wave's 16 rows (rows live at lane bits 2..5)
  f32x4 sq[4], sk[4];
#pragma unroll
  for (int j = 0; j < 4; ++j) { sq[j] = qv[j]; sk[j] = kv[j]; }
#pragma unroll
  for (int off = 4; off <= 32; off <<= 1)
#pragma unroll
    for (int j = 0; j < 4; ++j)
#pragma unroll
      for (int c = 0; c < 4; ++c) {
        sq[j][c] += __shfl_xor(sq[j][c], off);
        sk[j][c] += __shfl_xor(sk[j][c], off);
      }
  if ((lane & 60) == 0) {  // lanes 0..3, one per col group
#pragma unroll
    for (int j = 0; j < 4; ++j) {
      *(f32x4*)&colsq[w * 64 + cg + 4 * j] = sq[j];
      *(f32x4*)&colsk[w * 64 + cg + 4 * j] = sk[j];
    }
  }
  __syncthreads();  // barrier 1: partial sums visible

  f32x4 mqv[4], mkv[4];
#pragma unroll
  for (int j = 0; j < 4; ++j) {
    f32x4 aq = {0.f, 0.f, 0.f, 0.f}, ak = {0.f, 0.f, 0.f, 0.f};
#pragma unroll
    for (int ww = 0; ww < 4; ++ww) {
      aq += *(const f32x4*)&colsq[ww * 64 + cg + 4 * j];
      ak += *(const f32x4*)&colsk[ww * 64 + cg + 4 * j];
    }
    mqv[j] = aq * (1.0f / 64.0f);
    mkv[j] = ak * (1.0f / 64.0f);
  }
  if (w == 0 && (lane & 60) == 0)
#pragma unroll
    for (int j = 0; j < 4; ++j) *(f32x4*)&mq[cg + 4 * j] = mqv[j];

  // center, split hi/lo, store to shared LDS
#pragma unroll
  for (int half = 0; half < 2; ++half) {
    bf16x8 qh8, ql8, k8;
#pragma unroll
    for (int jj = 0; jj < 8; ++jj) {
      int j = half * 2 + (jj >> 2), c = jj & 3;
      float cq = qv[j][c] - mqv[j][c];
      short hi = f2b(cq);
      qh8[jj] = hi;
      ql8[jj] = f2b(cq - b2f(hi));
      k8[jj]  = f2b(kv[j][c] - mkv[j][c]);
    }
    *(bf16x8*)&XqH[crow][cg + 8 * half] = qh8;
    *(bf16x8*)&XqL[crow][cg + 8 * half] = ql8;
    *(bf16x8*)&Xk [crow][cg + 8 * half] = k8;
  }
  __syncthreads();  // barrier 2: Xc buffers + mq visible. No more barriers.

  // ================= per-head phase (wave-private) ==========================
  // rho[d=lane] = mu_q . Wr[:, h*64+lane] + br[h*64+lane]
  float rho;
  {
    const short* wrr = ws + WRT + (h * 64 + lane) * 64;
    float acc = br[h * 64 + lane];
#pragma unroll
    for (int e8 = 0; e8 < 8; ++e8) {
      bf16x8 w8 = *(const bf16x8*)(wrr + e8 * 8);
#pragma unroll
      for (int j = 0; j < 8; ++j) acc += mq[e8 * 8 + j] * b2f(w8[j]);
    }
    rho = acc;
  }
  float rr[4];
#pragma unroll
  for (int nt = 0; nt < 4; ++nt) rr[nt] = __shfl(rho, nt * 16 + lc);

  // value A-fragments (uncentered, single bf16) straight from global
  bf16x8 xv[4][2];
#pragma unroll
  for (int mt = 0; mt < 4; ++mt)
#pragma unroll
    for (int kk = 0; kk < 2; ++kk) {
      const float* vp = value + ((size_t)b * 64 + mt * 16 + lc) * 64 + kk * 32 + quad * 8;
      f32x4 v0 = *(const f32x4*)vp, v1 = *(const f32x4*)(vp + 4);
#pragma unroll
      for (int j = 0; j < 4; ++j) { xv[mt][kk][j] = f2b(v0[j]); xv[mt][kk][4 + j] = f2b(v1[j]); }
    }

  // ---- unary: u = softmax_s( Xck @ Wu[:,h] )  (uniform shift cancels) ----
  float usm[4];
  {
    bf16x8 wu[2];
#pragma unroll
    for (int kk = 0; kk < 2; ++kk)
      wu[kk] = *(const bf16x8*)(ws + WU0 + h * 1024 + lc * 64 + kk * 32 + quad * 8);
    f32x4 aU[4];
#pragma unroll
    for (int nt = 0; nt < 4; ++nt) {
      aU[nt] = f32x4{0.f, 0.f, 0.f, 0.f};
#pragma unroll
      for (int kk = 0; kk < 2; ++kk) {
        bf16x8 xb = *(const bf16x8*)&Xk[nt * 16 + lc][kk * 32 + quad * 8];
        aU[nt] = MFMA16(wu[kk], xb, aU[nt]);
      }
    }
    float un[4];
#pragma unroll
    for (int nt = 0; nt < 4; ++nt) un[nt] = __shfl(aU[nt][0], lc);  // u[nt*16+lc]
    float um = fmaxf(fmaxf(un[0], un[1]), fmaxf(un[2], un[3]));
    um = fmaxf(um, __shfl_xor(um, 1)); um = fmaxf(um, __shfl_xor(um, 2));
    um = fmaxf(um, __shfl_xor(um, 4)); um = fmaxf(um, __shfl_xor(um, 8));
    float ue[4], us = 0.f;
#pragma unroll
    for (int nt = 0; nt < 4; ++nt) { ue[nt] = __expf(un[nt] - um); us += ue[nt]; }
    us += __shfl_xor(us, 1); us += __shfl_xor(us, 2);
    us += __shfl_xor(us, 4); us += __shfl_xor(us, 8);
    float uinv = __builtin_amdgcn_rcpf(us);
#pragma unroll
    for (int nt = 0; nt < 4; ++nt) usm[nt] = ue[nt] * uinv;
  }

  // ---- V = Xv @ Wv_h + bv, relayout to B-fragments per d-tile nt ----------
  // For each nt: compute V[:, nt*16..+15] (all 64 keys), stage V^T in the
  // 16-row slice (rows = d = lc, cols = key), read back vB[nt].
  bf16x8 vB[4][2];
#pragma unroll
  for (int nt = 0; nt < 4; ++nt) {
    bf16x8 wv8[2];
#pragma unroll
    for (int kk = 0; kk < 2; ++kk)
      wv8[kk] = *(const bf16x8*)(ws + WVT + (h * 64 + nt * 16 + lc) * 64 + kk * 32 + quad * 8);
    float bvv = bv[h * 64 + nt * 16 + lc];
#pragma unroll
    for (int mtk = 0; mtk < 4; ++mtk) {
      f32x4 acc = {0.f, 0.f, 0.f, 0.f};
#pragma unroll
      for (int kk = 0; kk < 2; ++kk) acc = MFMA16(xv[mtk][kk], wv8[kk], acc);
      s16x4 pk;
#pragma unroll
      for (int r = 0; r < 4; ++r) pk[r] = f2b(acc[r] + bvv);
      *(s16x4*)&slice[w][lc][mtk * 16 + quad * 4] = pk;  // V^T[d=lc][key]
    }
#pragma unroll
    for (int kk = 0; kk < 2; ++kk)
      vB[nt][kk] = *(const bf16x8*)&slice[w][lc][kk * 32 + quad * 8];
  }

  // ---- per q-tile fused chain: T -> L -> softmax/P -> out -----------------
  for (int mt = 0; mt < 4; ++mt) {
    bf16x8 xh[2], xl[2];
#pragma unroll
    for (int kk = 0; kk < 2; ++kk) {
      xh[kk] = *(const bf16x8*)&XqH[mt * 16 + lc][kk * 32 + quad * 8];
      xl[kk] = *(const bf16x8*)&XqL[mt * 16 + lc][kk * 32 + quad * 8];
    }

    // T(own 16 rows) = Xcq @ M_h (3-term hi/lo) -> slice
    {
      f32x4 aT[4];
#pragma unroll
      for (int nt = 0; nt < 4; ++nt) {
        f32x4 acc = {0.f, 0.f, 0.f, 0.f};
#pragma unroll
        for (int kk = 0; kk < 2; ++kk) {
          int off = h * 4096 + (nt * 16 + lc) * 64 + kk * 32 + quad * 8;
          bf16x8 mh = *(const bf16x8*)(ws + MTHI + off);
          bf16x8 ml = *(const bf16x8*)(ws + MTLO + off);
          acc = MFMA16(xh[kk], mh, acc);
          acc = MFMA16(xh[kk], ml, acc);
          acc = MFMA16(xl[kk], mh, acc);
        }
        aT[nt] = acc;
      }
#pragma unroll
      for (int nt = 0; nt < 4; ++nt)
#pragma unroll
        for (int r = 0; r < 4; ++r)
          slice[w][quad * 4 + r][nt * 16 + lc] = f2b(aT[nt][r]);
    }
    bf16x8 tA[2];
#pragma unroll
    for (int kk = 0; kk < 2; ++kk)
      tA[kk] = *(const bf16x8*)&slice[w][lc][kk * 32 + quad * 8];

    // L(own rows) = T @ Xck^T
    f32x4 aL[4];
#pragma unroll
    for (int nt = 0; nt < 4; ++nt) {
      f32x4 acc = {0.f, 0.f, 0.f, 0.f};
#pragma unroll
      for (int kk = 0; kk < 2; ++kk) {
        bf16x8 xkB = *(const bf16x8*)&Xk[nt * 16 + lc][kk * 32 + quad * 8];
        acc = MFMA16(tA[kk], xkB, acc);
      }
      aL[nt] = acc;
    }

    // row softmax + unary; P -> slice
#pragma unroll
    for (int r = 0; r < 4; ++r) {
      float m = fmaxf(fmaxf(aL[0][r], aL[1][r]), fmaxf(aL[2][r], aL[3][r]));
      m = fmaxf(m, __shfl_xor(m, 1)); m = fmaxf(m, __shfl_xor(m, 2));
      m = fmaxf(m, __shfl_xor(m, 4)); m = fmaxf(m, __shfl_xor(m, 8));
      float e0 = __expf(aL[0][r] - m), e1 = __expf(aL[1][r] - m);
      float e2 = __expf(aL[2][r] - m), e3 = __expf(aL[3][r] - m);
      float s = e0 + e1 + e2 + e3;
      s += __shfl_xor(s, 1); s += __shfl_xor(s, 2);
      s += __shfl_xor(s, 4); s += __shfl_xor(s, 8);
      float inv = __builtin_amdgcn_rcpf(s);
      slice[w][quad * 4 + r][lc]      = f2b(e0 * inv + usm[0]);
      slice[w][quad * 4 + r][16 + lc] = f2b(e1 * inv + usm[1]);
      slice[w][quad * 4 + r][32 + lc] = f2b(e2 * inv + usm[2]);
      slice[w][quad * 4 + r][48 + lc] = f2b(e3 * inv + usm[3]);
    }
    bf16x8 pA[2];
#pragma unroll
    for (int kk = 0; kk < 2; ++kk)
      pA[kk] = *(const bf16x8*)&slice[w][lc][kk * 32 + quad * 8];

    // out(own rows) = P @ V + Xcq @ Wr_h (2-term) + rho
#pragma unroll
    for (int nt = 0; nt < 4; ++nt) {
      f32x4 acc = {0.f, 0.f, 0.f, 0.f};
#pragma unroll
      for (int kk = 0; kk < 2; ++kk) {
        acc = MFMA16(pA[kk], vB[nt][kk], acc);
        bf16x8 wr8 = *(const bf16x8*)(ws + WRT + (h * 64 + nt * 16 + lc) * 64 + kk * 32 + quad * 8);
        acc = MFMA16(xh[kk], wr8, acc);
        acc = MFMA16(xl[kk], wr8, acc);
      }
      float* op = out + ((size_t)b * 64 + mt * 16 + quad * 4) * 256 + h * 64 + nt * 16 + lc;
#pragma unroll
      for (int r = 0; r < 4; ++r) op[(size_t)r * 256] = acc[r] + rr[nt];
    }
  }
}

extern "C" void kernel_launch(void* const* d_in, const int* in_sizes, int n_in,
                              void* d_out, int out_size, void* d_ws, size_t ws_size,
                              hipStream_t stream) {
  (void)in_sizes; (void)n_in; (void)out_size; (void)ws_size;
  const float* query = (const float*)d_in[0];
  const float* key_  = (const float*)d_in[1];
  const float* value = (const float*)d_in[2];
  const float* Wq    = (const float*)d_in[3];
  // d_in[4] = bq: cancels under mean-centering
  const float* Wk    = (const float*)d_in[5];
  // d_in[6] = bk: cancels under mean-centering
  const float* Wv    = (const float*)d_in[7];
  const float* bv    = (const float*)d_in[8];
  const float* Wu    = (const float*)d_in[9];
  // d_in[10] = bu: cancels in softmax over fields
  const float* Wr    = (const float*)d_in[11];
  const float* br    = (const float*)d_in[12];
  short* ws = (short*)d_ws;

  hipLaunchKernelGGL(prepass, dim3(64), dim3(256), 0, stream, Wq, Wk, Wv, Wr, Wu, ws);
  hipLaunchKernelGGL(attn_main, dim3(B_), dim3(256), 0, stream,
                     query, key_, value, bv, br, ws, (float*)d_out);
}